// Round 1
// baseline (117.222 us; speedup 1.0000x reference)
//
#include <hip/hip_runtime.h>

typedef short bf16x8 __attribute__((ext_vector_type(8)));
typedef float f32x4 __attribute__((ext_vector_type(4)));

#define MFMA16(a, b, c) __builtin_amdgcn_mfma_f32_16x16x32_bf16((a), (b), (c), 0, 0, 0)

__device__ __forceinline__ unsigned short f2b(float f) {
  union { float f; unsigned int u; } x; x.f = f;
  unsigned int r = x.u + 0x7FFFu + ((x.u >> 16) & 1u);
  return (unsigned short)(r >> 16);
}
__device__ __forceinline__ float b2f(unsigned short h) {
  union { unsigned int u; float f; } x; x.u = ((unsigned int)h) << 16;
  return x.f;
}

// ---------------- weight transpose+convert: W[512][512] f32 -> Wt[512n][512k] bf16
__global__ __launch_bounds__(256) void wtrans_kernel(
    const float* __restrict__ Wq, const float* __restrict__ Wk,
    const float* __restrict__ Wv, const float* __restrict__ Wo,
    short* __restrict__ Wt) {
  __shared__ float tile[64][65];
  const int z = blockIdx.z;
  const float* W = (z == 0) ? Wq : (z == 1) ? Wk : (z == 2) ? Wv : Wo;
  const int k0 = blockIdx.x * 64, n0 = blockIdx.y * 64;
  const int t = threadIdx.x;
  const int r = t >> 4, cc = (t & 15) * 4;
#pragma unroll
  for (int it = 0; it < 4; ++it) {
    int row = r + it * 16;
    const float4 v = *(const float4*)(W + (k0 + row) * 512 + n0 + cc);
    tile[row][cc + 0] = v.x; tile[row][cc + 1] = v.y;
    tile[row][cc + 2] = v.z; tile[row][cc + 3] = v.w;
  }
  __syncthreads();
  short* out = Wt + z * (512 * 512);
#pragma unroll
  for (int it = 0; it < 4; ++it) {
    int nrow = r + it * 16;
    unsigned int u0 = (unsigned int)f2b(tile[cc + 0][nrow]) | ((unsigned int)f2b(tile[cc + 1][nrow]) << 16);
    unsigned int u1 = (unsigned int)f2b(tile[cc + 2][nrow]) | ((unsigned int)f2b(tile[cc + 3][nrow]) << 16);
    uint2 uv; uv.x = u0; uv.y = u1;
    *(uint2*)(out + (n0 + nrow) * 512 + k0 + cc) = uv;
  }
}

// ---------------- shared GEMM mainloop: C(128x128) = A(f32,[8192][512]) * W (Wt bf16 [n][k])
__device__ __forceinline__ void gemm_core(
    const float* __restrict__ A, const short* __restrict__ Wt,
    short (*Al)[72], short (*Bl)[72],
    int m0, int n0, int t, f32x4 acc[4][4]) {
  const int lane = t & 63, w = t >> 6;
  const int c = lane & 15, g = lane >> 4;
  const int wr = w >> 1, wc = w & 1;
  for (int kt = 0; kt < 8; ++kt) {
#pragma unroll
    for (int it = 0; it < 4; ++it) {
      int idx = it * 256 + t;
      int row = idx >> 3, col8 = (idx & 7) << 3;
      const float* src = A + (m0 + row) * 512 + kt * 64 + col8;
      float4 v0 = *(const float4*)src;
      float4 v1 = *(const float4*)(src + 4);
      bf16x8 sv;
      sv[0] = (short)f2b(v0.x); sv[1] = (short)f2b(v0.y);
      sv[2] = (short)f2b(v0.z); sv[3] = (short)f2b(v0.w);
      sv[4] = (short)f2b(v1.x); sv[5] = (short)f2b(v1.y);
      sv[6] = (short)f2b(v1.z); sv[7] = (short)f2b(v1.w);
      *(bf16x8*)(&Al[row][col8]) = sv;
      *(bf16x8*)(&Bl[row][col8]) = *(const bf16x8*)(Wt + (n0 + row) * 512 + kt * 64 + col8);
    }
    __syncthreads();
#pragma unroll
    for (int kc = 0; kc < 2; ++kc) {
      bf16x8 af[4], bfr[4];
#pragma unroll
      for (int mi = 0; mi < 4; ++mi) af[mi] = *(const bf16x8*)(&Al[wr * 64 + mi * 16 + c][kc * 32 + 8 * g]);
#pragma unroll
      for (int ni = 0; ni < 4; ++ni) bfr[ni] = *(const bf16x8*)(&Bl[wc * 64 + ni * 16 + c][kc * 32 + 8 * g]);
#pragma unroll
      for (int mi = 0; mi < 4; ++mi)
#pragma unroll
        for (int ni = 0; ni < 4; ++ni)
          acc[mi][ni] = MFMA16(af[mi], bfr[ni], acc[mi][ni]);
    }
    __syncthreads();
  }
}

// ---------------- projections: z=0 Qp, z=1 Kp (bf16 [8192][512]), z=2 Vt (bf16 [B][H][64][1024])
__global__ __launch_bounds__(256) void proj_kernel(
    const float* __restrict__ Q, const float* __restrict__ K,
    const short* __restrict__ Wt4,
    const float* __restrict__ bq, const float* __restrict__ bk, const float* __restrict__ bv,
    const float* __restrict__ maskf,
    short* __restrict__ Qp, short* __restrict__ Kp, short* __restrict__ Vt) {
  __shared__ short Al[128][72];
  __shared__ short Bl[128][72];
  const int z = blockIdx.z;
  const float* A = (z == 0) ? Q : K;
  const short* Wt = Wt4 + z * (512 * 512);
  const float* bias = (z == 0) ? bq : (z == 1) ? bk : bv;
  const int m0 = blockIdx.x * 128, n0 = blockIdx.y * 128;
  const int t = threadIdx.x;
  const f32x4 zz = {0.f, 0.f, 0.f, 0.f};
  f32x4 acc[4][4];
#pragma unroll
  for (int mi = 0; mi < 4; ++mi)
#pragma unroll
    for (int ni = 0; ni < 4; ++ni) acc[mi][ni] = zz;
  gemm_core(A, Wt, Al, Bl, m0, n0, t, acc);

  const int lane = t & 63, w = t >> 6;
  const int c = lane & 15, g = lane >> 4;
  const int wr = w >> 1, wc = w & 1;
  float mk[4][4];
#pragma unroll
  for (int mi = 0; mi < 4; ++mi) {
    int mbase = m0 + wr * 64 + mi * 16 + 4 * g;
#pragma unroll
    for (int i = 0; i < 4; ++i) mk[mi][i] = maskf[mbase + i];
  }
  if (z < 2) {
    short* out = (z == 0) ? Qp : Kp;
#pragma unroll
    for (int ni = 0; ni < 4; ++ni) {
      int n = n0 + wc * 64 + ni * 16 + c;
      float bval = bias[n];
#pragma unroll
      for (int mi = 0; mi < 4; ++mi) {
        int mbase = m0 + wr * 64 + mi * 16 + 4 * g;
#pragma unroll
        for (int i = 0; i < 4; ++i)
          out[(mbase + i) * 512 + n] = (short)f2b((acc[mi][ni][i] + bval) * mk[mi][i]);
      }
    }
  } else {
#pragma unroll
    for (int ni = 0; ni < 4; ++ni) {
      int n = n0 + wc * 64 + ni * 16 + c;
      int h = n >> 6, d = n & 63;
      float bval = bias[n];
#pragma unroll
      for (int mi = 0; mi < 4; ++mi) {
        int mbase = m0 + wr * 64 + mi * 16 + 4 * g;
        int bi = mbase >> 10, seq0 = mbase & 1023;
        unsigned int u0 = (unsigned int)f2b((acc[mi][ni][0] + bval) * mk[mi][0]) |
                          ((unsigned int)f2b((acc[mi][ni][1] + bval) * mk[mi][1]) << 16);
        unsigned int u1 = (unsigned int)f2b((acc[mi][ni][2] + bval) * mk[mi][2]) |
                          ((unsigned int)f2b((acc[mi][ni][3] + bval) * mk[mi][3]) << 16);
        uint2 uv; uv.x = u0; uv.y = u1;
        *(uint2*)(Vt + ((bi * 8 + h) * 64 + d) * 1024 + seq0) = uv;
      }
    }
  }
}

// ---------------- flash attention per (h,b), QBLK=64 (wave=16 rows), KV tile 64
__global__ __launch_bounds__(256) void attn_kernel(
    const short* __restrict__ Qp, const short* __restrict__ Kp,
    const short* __restrict__ Vt, const float* __restrict__ mask,
    float* __restrict__ Ob) {
  __shared__ short Kl[64][72];
  __shared__ short Vl[64][72];
  __shared__ short Pl[4][16][72];
  const int t = threadIdx.x, lane = t & 63, w = t >> 6;
  const int c = lane & 15, g = lane >> 4;
  const int qt = blockIdx.x, hb = blockIdx.y;
  const int b = hb & 7, h = hb >> 3;
  const int n0 = qt * 64;
  const float scale = 0.04419417382415922f;  // 1/sqrt(512)

  bf16x8 qf0, qf1;
  {
    const short* qptr = Qp + ((b * 1024 + n0 + w * 16 + c) * 512 + h * 64 + 8 * g);
    qf0 = *(const bf16x8*)qptr;
    qf1 = *(const bf16x8*)(qptr + 32);
  }
  float runmax = -1e30f, lrun = 0.f;
  const f32x4 zz = {0.f, 0.f, 0.f, 0.f};
  f32x4 o[4];
  o[0] = zz; o[1] = zz; o[2] = zz; o[3] = zz;

  for (int kvt = 0; kvt < 16; ++kvt) {
#pragma unroll
    for (int it = 0; it < 2; ++it) {
      int idx = it * 256 + t;
      int row = idx >> 3, col8 = (idx & 7) << 3;
      *(bf16x8*)(&Kl[row][col8]) = *(const bf16x8*)(Kp + ((b * 1024 + kvt * 64 + row) * 512 + h * 64 + col8));
      *(bf16x8*)(&Vl[row][col8]) = *(const bf16x8*)(Vt + (((b * 8 + h) * 64 + row) * 1024 + kvt * 64 + col8));
    }
    __syncthreads();

    // S^T = K * q^T : lane holds P-row q=c, kv = 16j + 4g + i
    f32x4 s[4];
#pragma unroll
    for (int j = 0; j < 4; ++j) {
      f32x4 sj = zz;
      sj = MFMA16(*(const bf16x8*)(&Kl[16 * j + c][8 * g]), qf0, sj);
      sj = MFMA16(*(const bf16x8*)(&Kl[16 * j + c][32 + 8 * g]), qf1, sj);
      s[j] = sj;
    }

    float mt = -1e30f;
#pragma unroll
    for (int j = 0; j < 4; ++j)
      mt = fmaxf(mt, fmaxf(fmaxf(s[j][0], s[j][1]), fmaxf(s[j][2], s[j][3])));
    mt = fmaxf(mt, __shfl_xor(mt, 16));
    mt = fmaxf(mt, __shfl_xor(mt, 32));
    float newmax = fmaxf(runmax, mt);
    float factor = __expf(scale * (runmax - newmax));
    runmax = newmax;

    float tsum = 0.f;
#pragma unroll
    for (int j = 0; j < 4; ++j) {
      float4 m2 = *(const float4*)(mask + b * 1024 + kvt * 64 + 16 * j + 4 * g);
      float p0 = __expf(scale * (s[j][0] - runmax)) * m2.x;
      float p1 = __expf(scale * (s[j][1] - runmax)) * m2.y;
      float p2 = __expf(scale * (s[j][2] - runmax)) * m2.z;
      float p3 = __expf(scale * (s[j][3] - runmax)) * m2.w;
      tsum += (p0 + p1) + (p2 + p3);
      *(unsigned int*)(&Pl[w][c][16 * j + 4 * g]) = (unsigned int)f2b(p0) | ((unsigned int)f2b(p1) << 16);
      *(unsigned int*)(&Pl[w][c][16 * j + 4 * g + 2]) = (unsigned int)f2b(p2) | ((unsigned int)f2b(p3) << 16);
    }
    tsum += __shfl_xor(tsum, 16);
    tsum += __shfl_xor(tsum, 32);
    lrun = lrun * factor + tsum;

#pragma unroll
    for (int i = 0; i < 4; ++i) {
      float fi = __shfl(factor, 4 * g + i);
      o[0][i] *= fi; o[1][i] *= fi; o[2][i] *= fi; o[3][i] *= fi;
    }

#pragma unroll
    for (int ks = 0; ks < 2; ++ks) {
      bf16x8 pa = *(const bf16x8*)(&Pl[w][c][ks * 32 + 8 * g]);
#pragma unroll
      for (int nb = 0; nb < 4; ++nb) {
        bf16x8 vb = *(const bf16x8*)(&Vl[c + 16 * nb][ks * 32 + 8 * g]);
        o[nb] = MFMA16(pa, vb, o[nb]);
      }
    }
    __syncthreads();
  }

  float lr[4], mk1[4];
#pragma unroll
  for (int i = 0; i < 4; ++i) {
    lr[i] = __shfl(lrun, 4 * g + i);
    mk1[i] = mask[b * 1024 + n0 + w * 16 + 4 * g + i];
  }
#pragma unroll
  for (int nb = 0; nb < 4; ++nb) {
    int colg = h * 64 + 16 * nb + c;
#pragma unroll
    for (int i = 0; i < 4; ++i) {
      int row = n0 + w * 16 + 4 * g + i;
      float att = o[nb][i] / (lr[i] + 1e-16f);
      float qv = b2f(*(const unsigned short*)(Qp + (b * 1024 + row) * 512 + colg));
      Ob[(b * 1024 + row) * 512 + colg] = qv + mk1[i] * att;
    }
  }
}

// ---------------- final: out = Ob + relu((Ob@Wo + bo) * mask)
__global__ __launch_bounds__(256) void final_kernel(
    const float* __restrict__ Ob, const short* __restrict__ Wto,
    const float* __restrict__ bo, const float* __restrict__ maskf,
    float* __restrict__ out) {
  __shared__ short Al[128][72];
  __shared__ short Bl[128][72];
  const int m0 = blockIdx.x * 128, n0 = blockIdx.y * 128;
  const int t = threadIdx.x;
  const f32x4 zz = {0.f, 0.f, 0.f, 0.f};
  f32x4 acc[4][4];
#pragma unroll
  for (int mi = 0; mi < 4; ++mi)
#pragma unroll
    for (int ni = 0; ni < 4; ++ni) acc[mi][ni] = zz;
  gemm_core(Ob, Wto, Al, Bl, m0, n0, t, acc);

  const int lane = t & 63, w = t >> 6;
  const int c = lane & 15, g = lane >> 4;
  const int wr = w >> 1, wc = w & 1;
  float mk[4][4];
#pragma unroll
  for (int mi = 0; mi < 4; ++mi) {
    int mbase = m0 + wr * 64 + mi * 16 + 4 * g;
#pragma unroll
    for (int i = 0; i < 4; ++i) mk[mi][i] = maskf[mbase + i];
  }
#pragma unroll
  for (int ni = 0; ni < 4; ++ni) {
    int n = n0 + wc * 64 + ni * 16 + c;
    float bval = bo[n];
#pragma unroll
    for (int mi = 0; mi < 4; ++mi) {
      int mbase = m0 + wr * 64 + mi * 16 + 4 * g;
#pragma unroll
      for (int i = 0; i < 4; ++i) {
        float v = (acc[mi][ni][i] + bval) * mk[mi][i];
        v = fmaxf(v, 0.f);
        int off = (mbase + i) * 512 + n;
        out[off] = Ob[off] + v;
      }
    }
  }
}

extern "C" void kernel_launch(void* const* d_in, const int* in_sizes, int n_in,
                              void* d_out, int out_size, void* d_ws, size_t ws_size,
                              hipStream_t stream) {
  (void)in_sizes; (void)n_in; (void)out_size; (void)ws_size;
  const float* Q    = (const float*)d_in[0];
  const float* K    = (const float*)d_in[1];
  const float* mask = (const float*)d_in[2];
  const float* Wq   = (const float*)d_in[3];
  const float* bq   = (const float*)d_in[4];
  const float* Wk   = (const float*)d_in[5];
  const float* bk   = (const float*)d_in[6];
  const float* Wv   = (const float*)d_in[7];
  const float* bv   = (const float*)d_in[8];
  const float* Wo   = (const float*)d_in[9];
  const float* bo   = (const float*)d_in[10];

  char* ws = (char*)d_ws;
  short* Wt4 = (short*)ws;                       // 4 x 512x512 bf16  (2 MiB)
  short* Qp  = (short*)(ws + 2097152);           // 8192x512 bf16     (8 MiB)
  short* Kp  = (short*)(ws + 10485760);          // 8192x512 bf16     (8 MiB)
  short* Vt  = (short*)(ws + 18874368);          // [8][8][64][1024] bf16 (8 MiB)
  float* Ob  = (float*)(ws + 27262976);          // 8192x512 f32      (16 MiB)
  float* out = (float*)d_out;

  wtrans_kernel<<<dim3(8, 8, 4), 256, 0, stream>>>(Wq, Wk, Wv, Wo, Wt4);
  proj_kernel<<<dim3(64, 4, 3), 256, 0, stream>>>(Q, K, Wt4, bq, bk, bv, mask, Qp, Kp, Vt);
  attn_kernel<<<dim3(16, 64), 256, 0, stream>>>(Qp, Kp, Vt, mask, Ob);
  final_kernel<<<dim3(64, 4), 256, 0, stream>>>(Ob, Wt4 + 3 * 512 * 512, bo, mask, out);
}